// Round 1
// baseline (591.043 us; speedup 1.0000x reference)
//
#include <hip/hip_runtime.h>

typedef __attribute__((ext_vector_type(8))) short short8;
typedef __attribute__((ext_vector_type(4))) float f32x4;
typedef __attribute__((ext_vector_type(4))) unsigned short ushx4;

#define E_EDGES 800000
#define TILE 32
#define NTILES (E_EDGES / TILE)

// ws layout in ushort (bf16) units
#define WS_TSRC 0
#define WS_TDST 12288
#define WS_TSTEP 24576
#define WS_TEQ 27136
#define WS_W2T 27392      // [n=0..127][k=0..127], W2T[n][k] = W[256+k][n]
#define WS_WRBFT 43776    // [n=0..127][k=0..31],  WrbfT[n][k] = k<6 ? W_rbf[k][n] : 0

__device__ __forceinline__ unsigned short f2bf(float f) {
    unsigned int u = __float_as_uint(f);
    u += 0x7fffu + ((u >> 16) & 1u);   // round-to-nearest-even
    return (unsigned short)(u >> 16);
}
__device__ __forceinline__ float bf2f(unsigned short u) {
    return __uint_as_float(((unsigned int)u) << 16);
}
__device__ __forceinline__ float silu_f(float v) {
    return v * __builtin_amdgcn_rcpf(1.0f + __expf(-v));
}

// ---------------- Kernel P: fold small-vocab gathers through W into tables ----
__global__ void precompute_kernel(const float* __restrict__ emb,
                                  const float* __restrict__ stept,
                                  const float* __restrict__ eqt,
                                  const float* __restrict__ Wrbf,
                                  const float* __restrict__ W,
                                  const float* __restrict__ bias,
                                  unsigned short* __restrict__ ws) {
    const int b = blockIdx.x;
    const int j = threadIdx.x;   // 128 threads
    if (b < 214) {
        const float* tab; int woff; unsigned short* outp; float acc = 0.f;
        if (b < 96)       { tab = emb   + b*128;        woff = 0;   outp = ws + WS_TSRC  + b*128; }
        else if (b < 192) { tab = emb   + (b-96)*128;   woff = 128; outp = ws + WS_TDST  + (b-96)*128; }
        else if (b < 212) { tab = stept + (b-192)*128;  woff = 384; outp = ws + WS_TSTEP + (b-192)*128; }
        else              { tab = eqt   + (b-212)*128;  woff = 512; outp = ws + WS_TEQ   + (b-212)*128; acc = bias[j]; }
        #pragma unroll 4
        for (int k = 0; k < 128; ++k)
            acc += tab[k] * W[(woff + k)*128 + j];
        outp[j] = f2bf(acc);
    } else {
        const int n = b - 214;   // 0..127
        ws[WS_W2T + n*128 + j] = f2bf(W[(256 + j)*128 + n]);
        if (j < 32)
            ws[WS_WRBFT + n*32 + j] = (j < 6) ? f2bf(Wrbf[j*128 + n]) : (unsigned short)0;
    }
}

// ---------------- Kernel M: persistent fused edge kernel ----------------------
__global__ __launch_bounds__(256, 3)
void edge_kernel(const int* __restrict__ Z, const int* __restrict__ stepv,
                 const int* __restrict__ src, const int* __restrict__ dst,
                 const int* __restrict__ equiv, const float* __restrict__ rbf,
                 const float* __restrict__ dvec, const float* __restrict__ brbf_g,
                 const unsigned short* __restrict__ ws, float* __restrict__ out) {
    __shared__ alignas(16) unsigned short rbf_stage[TILE*40];  // [e][k<32 bf16], pad 8
    __shared__ alignas(16) unsigned short rbf_a[TILE*136];     // [e][j] bf16, pad 8
    __shared__ alignas(16) float accbuf[TILE*132];             // [e][j] f32, pad 4
    __shared__ alignas(16) int4  meta[TILE];                   // ushort row offsets x4
    __shared__ float d_e[TILE];

    const int t = threadIdx.x;
    const int lane = t & 63;
    const int w = t >> 6;
    const int q = lane >> 4;      // quad
    const int r = lane & 15;
    const int mh = w >> 1;        // wave m-half: edges [mh*16, mh*16+16)
    const int nh = w & 1;         // wave n-half: cols  [nh*64, nh*64+64)
    const int arow = mh*16 + r;

    const unsigned short* W2T = ws + WS_W2T;
    const unsigned short* WRB = ws + WS_WRBFT;

    // block-invariant B-fragments in VGPRs
    short8 w2f[16];
    short8 wrbf[4];
    float  brbf[4];
    #pragma unroll
    for (int nt = 0; nt < 4; ++nt) {
        const int n = nh*64 + nt*16 + r;
        #pragma unroll
        for (int ks = 0; ks < 4; ++ks)
            w2f[nt*4+ks] = *(const short8*)(W2T + n*128 + ks*32 + q*8);
        wrbf[nt] = *(const short8*)(WRB + n*32 + q*8);
        brbf[nt] = brbf_g[n];
    }

    for (int tile = blockIdx.x; tile < NTILES; tile += gridDim.x) {
        const int base = tile * TILE;

        // ---- stage A: edge metadata + rbf tile (bf16, K-padded) into LDS ----
        if (t < 32) {
            const int e  = base + t;
            const int s  = src[e];
            const int dd = dst[e];
            const int qe = equiv[e];
            const int zs = Z[s];
            const int ss = stepv[s];
            const int zd = Z[dd];
            meta[t] = make_int4(zs*128, zd*128, ss*128, qe*128);
            d_e[t] = dvec[e];
        } else if (t < 64) {
            const int tt = t - 32;
            const float* rp = rbf + (base + tt)*6;
            short8 v;
            v[0] = (short)f2bf(rp[0]); v[1] = (short)f2bf(rp[1]);
            v[2] = (short)f2bf(rp[2]); v[3] = (short)f2bf(rp[3]);
            v[4] = (short)f2bf(rp[4]); v[5] = (short)f2bf(rp[5]);
            v[6] = 0; v[7] = 0;
            short8 zz = (short8)0;
            short8* dp = (short8*)(rbf_stage + tt*40);
            dp[0] = v; dp[1] = zz; dp[2] = zz; dp[3] = zz;
        }
        __syncthreads();

        // ---- mini GEMM: rbf_a = silu(rbf @ W_rbf + b_rbf), into A-layout LDS ----
        {
            short8 a0 = *(const short8*)(rbf_stage + arow*40 + q*8);
            #pragma unroll
            for (int nt = 0; nt < 4; ++nt) {
                f32x4 c = {0.f, 0.f, 0.f, 0.f};
                c = __builtin_amdgcn_mfma_f32_16x16x32_bf16(a0, wrbf[nt], c, 0, 0, 0);
                const int col = nh*64 + nt*16 + r;
                #pragma unroll
                for (int reg = 0; reg < 4; ++reg) {
                    const int row = mh*16 + q*4 + reg;     // C/D: row = quad*4+reg
                    rbf_a[row*136 + col] = f2bf(silu_f(c[reg] + brbf[nt]));
                }
            }
        }
        __syncthreads();

        // ---- main GEMM: acc = rbf_a @ W2 (K=128) ----
        f32x4 acc[4];
        #pragma unroll
        for (int nt = 0; nt < 4; ++nt) acc[nt] = (f32x4){0.f, 0.f, 0.f, 0.f};
        #pragma unroll
        for (int ks = 0; ks < 4; ++ks) {
            short8 a = *(const short8*)(rbf_a + arow*136 + ks*32 + q*8);
            #pragma unroll
            for (int nt = 0; nt < 4; ++nt)
                acc[nt] = __builtin_amdgcn_mfma_f32_16x16x32_bf16(a, w2f[nt*4+ks], acc[nt], 0, 0, 0);
        }
        // scatter acc to LDS for coalesced epilogue
        #pragma unroll
        for (int nt = 0; nt < 4; ++nt) {
            const int col = nh*64 + nt*16 + r;
            #pragma unroll
            for (int reg = 0; reg < 4; ++reg)
                accbuf[(mh*16 + q*4 + reg)*132 + col] = acc[nt][reg];
        }
        __syncthreads();

        // ---- epilogue: + table gathers, silu, coalesced float4 stores ----
        #pragma unroll
        for (int sph = 0; sph < 4; ++sph) {
            const int eloc = sph*8 + (t >> 5);
            const int j0 = (t & 31) * 4;
            f32x4 a4 = *(const f32x4*)(accbuf + eloc*132 + j0);
            const int4 mo = meta[eloc];
            ushx4 u0 = *(const ushx4*)(ws + WS_TSRC  + mo.x + j0);
            ushx4 u1 = *(const ushx4*)(ws + WS_TDST  + mo.y + j0);
            ushx4 u2 = *(const ushx4*)(ws + WS_TSTEP + mo.z + j0);
            ushx4 u3 = *(const ushx4*)(ws + WS_TEQ   + mo.w + j0);
            f32x4 res;
            #pragma unroll
            for (int i = 0; i < 4; ++i) {
                float v = a4[i] + bf2f(u0[i]) + bf2f(u1[i]) + bf2f(u2[i]) + bf2f(u3[i]);
                res[i] = silu_f(v);
            }
            *(f32x4*)(out + base*128 + sph*1024 + t*4) = res;
        }
        // rbf_env: bessel * envelope (pure fp32, 6 per edge)
        if (t < 192) {
            const int eloc = t / 6;
            const int rr = t - eloc*6;
            const float x = d_e[eloc] * 0.2f;
            const float inv = __builtin_amdgcn_rcpf(x);
            const float x2 = x*x;
            const float x5 = x2*x2*x;
            const float env = inv + x5*(-28.f + x*(48.f - 21.f*x));
            const float bess = __sinf(x * (3.14159265358979f * (rr + 1))) * inv;
            out[(long)E_EDGES*128 + (base + eloc)*6 + rr] = env * bess;
        }
        __syncthreads();   // protect meta/rbf_stage/accbuf for next tile
    }
}

extern "C" void kernel_launch(void* const* d_in, const int* in_sizes, int n_in,
                              void* d_out, int out_size, void* d_ws, size_t ws_size,
                              hipStream_t stream) {
    const int*   Z     = (const int*)d_in[0];
    const int*   stepv = (const int*)d_in[1];
    const int*   src   = (const int*)d_in[2];
    const int*   dst   = (const int*)d_in[3];
    const int*   equiv = (const int*)d_in[4];
    const float* rbf   = (const float*)d_in[5];
    const float* dvec  = (const float*)d_in[6];
    const float* emb   = (const float*)d_in[7];
    const float* stept = (const float*)d_in[8];
    const float* eqt   = (const float*)d_in[9];
    const float* Wrbf  = (const float*)d_in[10];
    const float* brbf  = (const float*)d_in[11];
    const float* W     = (const float*)d_in[12];
    const float* bias  = (const float*)d_in[13];
    unsigned short* ws = (unsigned short*)d_ws;
    float* out = (float*)d_out;

    precompute_kernel<<<342, 128, 0, stream>>>(emb, stept, eqt, Wrbf, W, bias, ws);
    edge_kernel<<<768, 256, 0, stream>>>(Z, stepv, src, dst, equiv, rbf, dvec, brbf, ws, out);
}

// Round 2
// 533.145 us; speedup vs baseline: 1.1086x; 1.1086x over previous
//
#include <hip/hip_runtime.h>

typedef __attribute__((ext_vector_type(8))) short short8;
typedef __attribute__((ext_vector_type(4))) float f32x4;
typedef __attribute__((ext_vector_type(4))) unsigned short ushx4;
typedef __attribute__((ext_vector_type(8))) unsigned short ushx8;

#define E_EDGES 800000
#define TILE 64
#define NTILES (E_EDGES / TILE)   // 12500 exact

// ws layout, ushort units (tables)
#define WS_TSRC 0
#define WS_TDST 12288
#define WS_TSTEP 24576
#define WS_TEQ 27136
#define WS_W2T 27392      // [n=0..127][k=0..127], W2T[n][k] = W[256+k][n]
#define WS_WRBFT 43776    // [n=0..127][k=0..31],  zero-padded past k=6
// byte offsets for per-edge prestage (tables end at 95744 B)
#define WSB_META 131072u                    // int4[E] = 12.8 MB
#define WSB_RBF8 (WSB_META + 16u*E_EDGES)   // ushx8[E] = 12.8 MB

__device__ __forceinline__ unsigned short f2bf(float f) {
    unsigned int u = __float_as_uint(f);
    u += 0x7fffu + ((u >> 16) & 1u);   // RNE
    return (unsigned short)(u >> 16);
}
__device__ __forceinline__ float bf2f(unsigned short u) {
    return __uint_as_float(((unsigned int)u) << 16);
}
__device__ __forceinline__ float silu_f(float v) {
    return v * __builtin_amdgcn_rcpf(1.0f + __expf(-v));
}

// ---------------- Kernel P: fold small-vocab gathers through W into tables ----
__global__ void precompute_kernel(const float* __restrict__ emb,
                                  const float* __restrict__ stept,
                                  const float* __restrict__ eqt,
                                  const float* __restrict__ Wrbf,
                                  const float* __restrict__ W,
                                  const float* __restrict__ bias,
                                  unsigned short* __restrict__ ws) {
    const int b = blockIdx.x;
    const int j = threadIdx.x;   // 128 threads
    if (b < 214) {
        const float* tab; int woff; unsigned short* outp; float acc = 0.f;
        if (b < 96)       { tab = emb   + b*128;        woff = 0;   outp = ws + WS_TSRC  + b*128; }
        else if (b < 192) { tab = emb   + (b-96)*128;   woff = 128; outp = ws + WS_TDST  + (b-96)*128; }
        else if (b < 212) { tab = stept + (b-192)*128;  woff = 384; outp = ws + WS_TSTEP + (b-192)*128; }
        else              { tab = eqt   + (b-212)*128;  woff = 512; outp = ws + WS_TEQ   + (b-212)*128; acc = bias[j]; }
        #pragma unroll 4
        for (int k = 0; k < 128; ++k)
            acc += tab[k] * W[(woff + k)*128 + j];
        outp[j] = f2bf(acc);
    } else {
        const int n = b - 214;   // 0..127
        ws[WS_W2T + n*128 + j] = f2bf(W[(256 + j)*128 + n]);
        if (j < 32)
            ws[WS_WRBFT + n*32 + j] = (j < 6) ? f2bf(Wrbf[j*128 + n]) : (unsigned short)0;
    }
}

// ---------------- Kernel I: per-edge prestage (meta, rbf->bf16, rbf_env) ------
__global__ __launch_bounds__(256)
void index_kernel(const int* __restrict__ Z, const int* __restrict__ stepv,
                  const int* __restrict__ src, const int* __restrict__ dst,
                  const int* __restrict__ equiv, const float* __restrict__ rbf,
                  const float* __restrict__ dvec,
                  unsigned char* __restrict__ wsb, float* __restrict__ out) {
    __shared__ float rl[1536];
    __shared__ float el[1536];
    const int t = threadIdx.x;
    const int B0 = blockIdx.x * 256;
    const int e = B0 + t;
    // coalesced rbf stage
    #pragma unroll
    for (int i = 0; i < 6; ++i) rl[t + i*256] = rbf[B0*6 + t + i*256];
    const int s  = src[e];
    const int dd = dst[e];
    const int qe = equiv[e];
    const float x = dvec[e] * 0.2f;
    int4* meta = (int4*)(wsb + WSB_META);
    meta[e] = make_int4(Z[s]*128, Z[dd]*128, stepv[s]*128, qe*128);
    // envelope * bessel into LDS (coalesced write-out later)
    const float inv = __builtin_amdgcn_rcpf(x);
    const float x2 = x*x;
    const float x5 = x2*x2*x;
    const float env = inv + x5*(-28.f + x*(48.f - 21.f*x));
    #pragma unroll
    for (int rr = 0; rr < 6; ++rr)
        el[t*6 + rr] = env * __sinf(x * (3.14159265358979f * (rr + 1))) * inv;
    __syncthreads();
    // rbf -> bf16 x8 (K-padded)
    ushx8 v;
    #pragma unroll
    for (int k = 0; k < 6; ++k) v[k] = f2bf(rl[t*6 + k]);
    v[6] = 0; v[7] = 0;
    ((ushx8*)(wsb + WSB_RBF8))[e] = v;
    #pragma unroll
    for (int i = 0; i < 6; ++i)
        out[(long)E_EDGES*128 + B0*6 + t + i*256] = el[t + i*256];
}

// ---------------- Kernel M: persistent fused edge kernel ----------------------
__global__ __launch_bounds__(256, 3)
void edge_kernel(const unsigned short* __restrict__ ws,
                 const unsigned char* __restrict__ wsb,
                 const float* __restrict__ brbf_g, float* __restrict__ out) {
    __shared__ alignas(16) unsigned short rbf_a[TILE*136];  // 17.4 KB, A-layout bf16
    __shared__ alignas(16) float sumbuf[TILE*132];          // 33.8 KB, table sums f32

    const int t = threadIdx.x;
    const int lane = t & 63;
    const int w = t >> 6;
    const int q = lane >> 4;
    const int r = lane & 15;
    const int mh = w >> 1;        // edge sub-tile [mh*16, +16)
    const int nh = w & 1;         // col half [nh*64, +64)
    const int arow = mh*16 + r;

    const unsigned short* W2T = ws + WS_W2T;
    const unsigned short* WRB = ws + WS_WRBFT;
    const int4* g_meta = (const int4*)(wsb + WSB_META);
    const ushx8* g_rbf8 = (const ushx8*)(wsb + WSB_RBF8);

    // block-invariant B-fragments in VGPRs
    short8 w2f[16];
    short8 wrbf[4];
    float  brbf[4];
    #pragma unroll
    for (int nt = 0; nt < 4; ++nt) {
        const int n = nh*64 + nt*16 + r;
        #pragma unroll
        for (int ks = 0; ks < 4; ++ks)
            w2f[nt*4+ks] = *(const short8*)(W2T + n*128 + ks*32 + q*8);
        wrbf[nt] = *(const short8*)(WRB + n*32 + q*8);
        brbf[nt] = brbf_g[n];
    }

    const int eloc = t & 63;          // sumbuf staging: one edge per lane
    const int jb = (t >> 6) * 32;     // each wave covers a 32-col band

    for (int tile = blockIdx.x; tile < NTILES; tile += gridDim.x) {
        const int base = tile * TILE;

        // ---- phase 1a: table-sum prestage (global gathers, L1/L2-resident) ----
        {
            const int4 mo = g_meta[base + eloc];
            float* srow = sumbuf + eloc*132;
            #pragma unroll
            for (int g = 0; g < 8; ++g) {
                const int j = jb + g*4;
                ushx4 u0 = *(const ushx4*)(ws + WS_TSRC  + mo.x + j);
                ushx4 u1 = *(const ushx4*)(ws + WS_TDST  + mo.y + j);
                ushx4 u2 = *(const ushx4*)(ws + WS_TSTEP + mo.z + j);
                ushx4 u3 = *(const ushx4*)(ws + WS_TEQ   + mo.w + j);
                f32x4 sv;
                #pragma unroll
                for (int i = 0; i < 4; ++i)
                    sv[i] = bf2f(u0[i]) + bf2f(u1[i]) + bf2f(u2[i]) + bf2f(u3[i]);
                *(f32x4*)(srow + j) = sv;
            }
        }

        // ---- phase 1b: mini-MFMA rbf_a = silu(rbf @ W_rbf + b), A-frag direct from global
        {
            short8 a0 = (short8)0;
            if (q == 0) a0 = *(const short8*)(g_rbf8 + base + arow);
            #pragma unroll
            for (int nt = 0; nt < 4; ++nt) {
                const float bb = brbf[nt];
                f32x4 c = {bb, bb, bb, bb};
                c = __builtin_amdgcn_mfma_f32_16x16x32_bf16(a0, wrbf[nt], c, 0, 0, 0);
                const int col = nh*64 + nt*16 + r;
                #pragma unroll
                for (int reg = 0; reg < 4; ++reg)
                    rbf_a[(mh*16 + q*4 + reg)*136 + col] = f2bf(silu_f(c[reg]));
            }
        }
        __syncthreads();

        // ---- phase 2: main MFMA (C init = table sums), silu, direct stores ----
        f32x4 acc[4];
        #pragma unroll
        for (int nt = 0; nt < 4; ++nt) {
            const int col = nh*64 + nt*16 + r;
            #pragma unroll
            for (int reg = 0; reg < 4; ++reg)
                acc[nt][reg] = sumbuf[(mh*16 + q*4 + reg)*132 + col];
        }
        #pragma unroll
        for (int ks = 0; ks < 4; ++ks) {
            short8 a = *(const short8*)(rbf_a + arow*136 + ks*32 + q*8);
            #pragma unroll
            for (int nt = 0; nt < 4; ++nt)
                acc[nt] = __builtin_amdgcn_mfma_f32_16x16x32_bf16(a, w2f[nt*4+ks], acc[nt], 0, 0, 0);
        }
        #pragma unroll
        for (int nt = 0; nt < 4; ++nt) {
            const int col = nh*64 + nt*16 + r;
            #pragma unroll
            for (int reg = 0; reg < 4; ++reg)
                out[(long)(base + mh*16 + q*4 + reg)*128 + col] = silu_f(acc[nt][reg]);
        }
        __syncthreads();   // protect sumbuf/rbf_a for next tile
    }
}

extern "C" void kernel_launch(void* const* d_in, const int* in_sizes, int n_in,
                              void* d_out, int out_size, void* d_ws, size_t ws_size,
                              hipStream_t stream) {
    const int*   Z     = (const int*)d_in[0];
    const int*   stepv = (const int*)d_in[1];
    const int*   src   = (const int*)d_in[2];
    const int*   dst   = (const int*)d_in[3];
    const int*   equiv = (const int*)d_in[4];
    const float* rbf   = (const float*)d_in[5];
    const float* dvec  = (const float*)d_in[6];
    const float* emb   = (const float*)d_in[7];
    const float* stept = (const float*)d_in[8];
    const float* eqt   = (const float*)d_in[9];
    const float* Wrbf  = (const float*)d_in[10];
    const float* brbf  = (const float*)d_in[11];
    const float* W     = (const float*)d_in[12];
    const float* bias  = (const float*)d_in[13];
    unsigned short* ws = (unsigned short*)d_ws;
    unsigned char* wsb = (unsigned char*)d_ws;
    float* out = (float*)d_out;

    precompute_kernel<<<342, 128, 0, stream>>>(emb, stept, eqt, Wrbf, W, bias, ws);
    index_kernel<<<3125, 256, 0, stream>>>(Z, stepv, src, dst, equiv, rbf, dvec, wsb, out);
    edge_kernel<<<768, 256, 0, stream>>>(ws, wsb, brbf, out);
}